// Round 16
// baseline (143.431 us; speedup 1.0000x reference)
//
#include <hip/hip_runtime.h>
#include <math.h>

#define CF 256
#define HID 170
#define NE 8
#define NTOK 512
#define K1 2304      // 256*9
#define K2P 1536     // 170*9 = 1530 padded to 1536
#define CAPACITY 161

typedef __bf16 bf16x8 __attribute__((ext_vector_type(8)));
typedef unsigned short u16x8 __attribute__((ext_vector_type(8)));
typedef float f32x4 __attribute__((ext_vector_type(4)));

__device__ __forceinline__ float silu_f(float x) { return x / (1.0f + expf(-x)); }
__device__ __forceinline__ float gelu_f(float x) {
    return 0.5f * x * (1.0f + erff(x * 0.70710678118654752f));
}

__device__ __forceinline__ unsigned short f2bf(float f) {
    unsigned int u = __float_as_uint(f);
    u = u + 0x7fffu + ((u >> 16) & 1u);
    return (unsigned short)(u >> 16);
}

// Cubic B-spline bases on uniform grid g(j) = (j-3)*0.4 - 1; denominators are k*h
__device__ __forceinline__ void bspline8(float x, float bs[8]) {
    float b[11];
#pragma unroll
    for (int j = 0; j < 11; ++j) {
        float g0 = (float)(j - 3) * 0.4f - 1.0f;
        float g1 = (float)(j - 2) * 0.4f - 1.0f;
        b[j] = (x >= g0 && x < g1) ? 1.0f : 0.0f;
    }
#pragma unroll
    for (int k = 1; k <= 3; ++k) {
        float inv = 2.5f / (float)k;  // 1/(k*0.4)
#pragma unroll
        for (int j = 0; j < 10 - (k - 1); ++j) {
            float gj   = (float)(j - 3) * 0.4f - 1.0f;
            float gjk1 = (float)(j - 2 + k) * 0.4f - 1.0f;
            b[j] = (x - gj) * inv * b[j] + (gjk1 - x) * inv * b[j + 1];
        }
    }
#pragma unroll
    for (int c = 0; c < 8; ++c) bs[c] = b[c];
}

// ---- 1. mega: pool (0..8191) + buildW1 + buildW2 ---------------------------
__global__ __launch_bounds__(256) void mega_front_kernel(const float* __restrict__ fpn,
                                                         const float* __restrict__ seg,
                                                         const float* __restrict__ bw1,
                                                         const float* __restrict__ sw1,
                                                         const float* __restrict__ sc1,
                                                         const float* __restrict__ bw2,
                                                         const float* __restrict__ sw2,
                                                         const float* __restrict__ sc2,
                                                         float* __restrict__ vec,
                                                         unsigned short* __restrict__ W1,
                                                         unsigned short* __restrict__ W2,
                                                         float* __restrict__ out) {
    int id = blockIdx.x, tid = threadIdx.x;
    if (id == 8192 && tid < 16) out[tid] = 0.0f;  // zero d_out for atomic finalize
    if (id < 8192) {
        // ---- pool: one block per (b, c, bd-octant); 8 float4 loads/thread ----
        int c = id & 255, bd = (id >> 8) & 3, b = id >> 10;
        const float* src = (c < 254) ? fpn + (size_t)(b * 254 + c) * 32768
                                     : seg + (size_t)(b * 2 + (c - 254)) * 32768;
        const float4* s4 = (const float4*)src + (size_t)bd * 8 * 256;
        float s = 0.0f;
#pragma unroll
        for (int it = 0; it < 8; ++it) {
            float4 v = s4[it * 256 + tid];
            s += v.x + v.y + v.z + v.w;
        }
        __shared__ float acc[16];
        if (tid < 16) acc[tid] = 0.0f;
        __syncthreads();
        int bh = tid >> 6, bw = (tid & 7) >> 1;
        atomicAdd(&acc[bh * 4 + bw], s);
        __syncthreads();
        if (tid < 16)
            vec[(size_t)(b * 64 + bd * 16 + tid) * CF + c] = acc[tid] * (1.0f / 512.0f);
    } else if (id < 8192 + NE * HID) {
        // ---- build W1 (augmented bf16) ----
        int r = id - 8192;
        int o = r % HID, e = r / HID, i = tid;
        size_t oi = (size_t)(e * HID + o) * CF + i;
        unsigned short* row = W1 + (size_t)(e * HID + o) * K1;
        row[i] = f2bf(bw1[oi]);
        float sc = sc1[oi];
        const float* sw = sw1 + oi * 8;
        u16x8 pk;
#pragma unroll
        for (int c = 0; c < 8; ++c) pk[c] = f2bf(sw[c] * sc);
        *(u16x8*)(row + CF + i * 8) = pk;
    } else {
        // ---- build W2 (augmented bf16, K padded to 1536) ----
        int r = id - (8192 + NE * HID);
        int o = r & 255, e = r >> 8, t = tid;
        unsigned short* row = W2 + (size_t)(e * CF + o) * K2P;
        if (t < HID) {
            size_t oi = (size_t)(e * CF + o) * HID + t;
            row[t] = f2bf(bw2[oi]);
            float sc = sc2[oi];
            const float* sw = sw2 + oi * 8;
            u16x8 pk;
#pragma unroll
            for (int c = 0; c < 8; ++c) pk[c] = f2bf(sw[c] * sc);
            *(u16x8*)(row + HID + t * 8) = pk;
        } else if (t < HID + 6) {
            row[HID * 9 + (t - HID)] = 0;
        }
    }
}

// ---- 2. per-token layernorm + router scores + A1 build + A2-pad zero -------
__global__ __launch_bounds__(256) void ln_score_a1_kernel(const float* __restrict__ vec,
                                                          const float* __restrict__ lnw,
                                                          const float* __restrict__ lnb,
                                                          const float* __restrict__ rw,
                                                          const float* __restrict__ rb,
                                                          float* __restrict__ scores,
                                                          unsigned short* __restrict__ A1,
                                                          unsigned short* __restrict__ A2) {
    int n = blockIdx.x, i = threadIdx.x;
    // zero A2 K-pad [1530,1536) for this token across all experts
    if (i < 48) {
        int e = i / 6, j = i - e * 6;
        A2[((size_t)e * NTOK + n) * K2P + HID * 9 + j] = 0;
    }
    float v = vec[(size_t)n * CF + i];
    float s1 = v, s2 = v * v;
#pragma unroll
    for (int off = 32; off > 0; off >>= 1) {
        s1 += __shfl_xor(s1, off);
        s2 += __shfl_xor(s2, off);
    }
    __shared__ float rs1[4], rs2[4];
    int lane = i & 63, wid = i >> 6;
    if (lane == 0) { rs1[wid] = s1; rs2[wid] = s2; }
    __syncthreads();
    float tot1 = rs1[0] + rs1[1] + rs1[2] + rs1[3];
    float tot2 = rs2[0] + rs2[1] + rs2[2] + rs2[3];
    float mu = tot1 * (1.0f / CF);
    float var = tot2 * (1.0f / CF) - mu * mu;
    float rsd = rsqrtf(var + 1e-5f);
    float xv = (v - mu) * rsd * lnw[i] + lnb[i];
    unsigned short* r = A1 + (size_t)n * K1;
    r[i] = f2bf(silu_f(xv));
    float bs[8]; bspline8(xv, bs);
    u16x8 pk;
#pragma unroll
    for (int c = 0; c < 8; ++c) pk[c] = f2bf(bs[c]);
    *(u16x8*)(r + CF + i * 8) = pk;
    float p[NE];
#pragma unroll
    for (int e = 0; e < NE; ++e) p[e] = xv * rw[e * CF + i];
#pragma unroll
    for (int off = 32; off > 0; off >>= 1)
#pragma unroll
        for (int e = 0; e < NE; ++e) p[e] += __shfl_xor(p[e], off);
    __shared__ float pacc[4][NE];
    if (lane == 0)
#pragma unroll
        for (int e = 0; e < NE; ++e) pacc[wid][e] = p[e];
    __syncthreads();
    if (i < NE)
        scores[n * NE + i] = pacc[0][i] + pacc[1][i] + pacc[2][i] + pacc[3][i] + rb[i];
}

// ---- 3. batched bf16 MFMA GEMM, LDS-FREE direct fragment loads -------------
// C[e] = A[e](M,K) * B[e](N,K)^T. Operands are L2/L3-resident, so each lane
// loads its MFMA fragments straight from global (16 rows x 64B per wave-load).
// No LDS staging, no barriers -> no per-K-step drain. 1D grid, bid%8 = expert
// (XCD-pinned). MODE 1: epilogue gelu->augmented A2; bid==NE*TPE runs topk.
template <int MODE, int NTX, int TPE>
__global__ __launch_bounds__(256) void gemm_mfma_kernel(
        const unsigned short* __restrict__ Ag, const unsigned short* __restrict__ Bg,
        float* __restrict__ C, unsigned short* __restrict__ A2,
        const float* __restrict__ scores, float* __restrict__ cw, float* __restrict__ conf,
        int N, int K, long sA, long sB, long sC, int ldc) {
    __shared__ int   ti0[NTOK], ti1[NTOK];
    __shared__ float tw0[NTOK], tw1[NTOK];
    int tid = threadIdx.x;
    int lane = tid & 63, w = tid >> 6;

    if (MODE == 1 && blockIdx.x >= NE * TPE) {
        // ---- topk (256 threads: 2 tokens each, then 4 waves x 2 experts) ----
#pragma unroll
        for (int half = 0; half < 2; ++half) {
            int t = half * 256 + tid;
            float m1 = -1e30f, m2 = -1e30f; int i1 = 0, i2 = 0;
#pragma unroll
            for (int e = 0; e < NE; ++e) {
                float sc = scores[t * NE + e];
                if (sc > m1) { m2 = m1; i2 = i1; m1 = sc; i1 = e; }
                else if (sc > m2) { m2 = sc; i2 = e; }
            }
            conf[t] = m1;
            float ew = expf(m2 - m1);
            ti0[t] = i1; ti1[t] = i2;
            tw0[t] = 1.0f / (1.0f + ew); tw1[t] = ew / (1.0f + ew);
        }
        __syncthreads();
#pragma unroll
        for (int e2 = 0; e2 < 2; ++e2) {
            int e = w * 2 + e2;
            int cnt = 0;
#pragma unroll
            for (int c = 0; c < NTOK / 64; ++c) {
                int t = c * 64 + lane;
                int h0 = (ti0[t] == e), h1 = (ti1[t] == e);
                int sel = h0 | h1;
                unsigned long long mask = __ballot(sel);
                int pos = cnt + (int)__popcll(mask & ((1ull << lane) - 1ull));
                float wv = 0.f;
                if (sel && pos < CAPACITY) wv = h0 ? tw0[t] : tw1[t];
                cw[e * NTOK + t] = wv;
                cnt += (int)__popcll(mask);
            }
        }
        return;
    }

    // XCD-pinned decode: expert = bid % 8 (1D round-robin -> same XCD)
    int bid = blockIdx.x;
    int e = bid & 7, t = bid >> 3;
    int m0 = (t / NTX) * 64, n0 = (t % NTX) * 64;
    const unsigned short* A = Ag + (size_t)e * sA;
    const unsigned short* B = Bg + (size_t)e * sB;
    int wr = w >> 1, wc = w & 1;
    int fr = lane & 15, fg = lane >> 4;

    // per-lane fragment base pointers (identical frag map to the LDS version:
    // A[m0+wr*32+mf*16+fr][k + fg*8], B[n0+wc*32+nf*16+fr][k + fg*8])
    int ar0 = m0 + wr * 32 + fr, ar1 = ar0 + 16;
    int bc0 = n0 + wc * 32 + fr, bc1 = bc0 + 16;
    int bb0 = bc0 < N ? bc0 : N - 1;  // clamp; garbage cols masked at C-write
    int bb1 = bc1 < N ? bc1 : N - 1;
    const unsigned short* pa0 = A + (size_t)ar0 * K + fg * 8;
    const unsigned short* pa1 = A + (size_t)ar1 * K + fg * 8;
    const unsigned short* pb0 = B + (size_t)bb0 * K + fg * 8;
    const unsigned short* pb1 = B + (size_t)bb1 * K + fg * 8;

    f32x4 acc[2][2];
#pragma unroll
    for (int i = 0; i < 2; ++i)
#pragma unroll
        for (int j = 0; j < 2; ++j)
#pragma unroll
            for (int r = 0; r < 4; ++r) acc[i][j][r] = 0.f;

    const int steps = K >> 5;  // 72 (gemm1) or 48 (gemm2)
    u16x8 a0 = *(const u16x8*)pa0;
    u16x8 a1 = *(const u16x8*)pa1;
    u16x8 b0 = *(const u16x8*)pb0;
    u16x8 b1 = *(const u16x8*)pb1;
#pragma unroll 4
    for (int s = 0; s < steps; ++s) {
        u16x8 na0 = a0, na1 = a1, nb0 = b0, nb1 = b1;
        if (s + 1 < steps) {
            int k0 = (s + 1) << 5;
            na0 = *(const u16x8*)(pa0 + k0);
            na1 = *(const u16x8*)(pa1 + k0);
            nb0 = *(const u16x8*)(pb0 + k0);
            nb1 = *(const u16x8*)(pb1 + k0);
        }
        acc[0][0] = __builtin_amdgcn_mfma_f32_16x16x32_bf16(
            __builtin_bit_cast(bf16x8, a0), __builtin_bit_cast(bf16x8, b0), acc[0][0], 0, 0, 0);
        acc[0][1] = __builtin_amdgcn_mfma_f32_16x16x32_bf16(
            __builtin_bit_cast(bf16x8, a0), __builtin_bit_cast(bf16x8, b1), acc[0][1], 0, 0, 0);
        acc[1][0] = __builtin_amdgcn_mfma_f32_16x16x32_bf16(
            __builtin_bit_cast(bf16x8, a1), __builtin_bit_cast(bf16x8, b0), acc[1][0], 0, 0, 0);
        acc[1][1] = __builtin_amdgcn_mfma_f32_16x16x32_bf16(
            __builtin_bit_cast(bf16x8, a1), __builtin_bit_cast(bf16x8, b1), acc[1][1], 0, 0, 0);
        a0 = na0; a1 = na1; b0 = nb0; b1 = nb1;
    }

    if (MODE == 1) {
#pragma unroll
        for (int mf = 0; mf < 2; ++mf)
#pragma unroll
            for (int nf = 0; nf < 2; ++nf)
#pragma unroll
                for (int r = 0; r < 4; ++r) {
                    int row = m0 + wr * 32 + mf * 16 + fg * 4 + r;  // token
                    int col = n0 + wc * 32 + nf * 16 + fr;          // hid
                    if (col < N) {
                        float g = gelu_f(acc[mf][nf][r]);
                        unsigned short* rr = A2 + ((size_t)e * NTOK + row) * K2P;
                        rr[col] = f2bf(silu_f(g));
                        float bs[8]; bspline8(g, bs);
                        u16x8 pk;
#pragma unroll
                        for (int c = 0; c < 8; ++c) pk[c] = f2bf(bs[c]);
                        *(u16x8*)(rr + HID + col * 8) = pk;
                    }
                }
    } else {
        float* Ce = C + (size_t)e * sC;
#pragma unroll
        for (int mf = 0; mf < 2; ++mf)
#pragma unroll
            for (int nf = 0; nf < 2; ++nf)
#pragma unroll
                for (int r = 0; r < 4; ++r) {
                    int row = m0 + wr * 32 + mf * 16 + fg * 4 + r;
                    int col = n0 + wc * 32 + nf * 16 + fr;
                    if (col < N) Ce[(size_t)row * ldc + col] = acc[mf][nf][r];
                }
    }
}

// ---- 4. combine + classifier KAN + atomic batch-softmax finalize -----------
__global__ __launch_bounds__(256) void combcls_kernel(const float* __restrict__ y,
                                                      const float* __restrict__ cw,
                                                      const float* __restrict__ conf,
                                                      const float* __restrict__ lnw,
                                                      const float* __restrict__ lnb,
                                                      const float* __restrict__ cbw,
                                                      const float* __restrict__ csw,
                                                      const float* __restrict__ csc,
                                                      float* __restrict__ out) {
    int n = blockIdx.x, i = threadIdx.x;
    float v = 0.f;
#pragma unroll
    for (int e = 0; e < NE; ++e)
        v += cw[e * NTOK + n] * y[((size_t)(e * NTOK + n)) * CF + i];
    float s1 = v, s2 = v * v;
#pragma unroll
    for (int off = 32; off > 0; off >>= 1) {
        s1 += __shfl_xor(s1, off);
        s2 += __shfl_xor(s2, off);
    }
    __shared__ float rA[4], rB[4], rP0[4], rP1[4];
    int lane = i & 63, wid = i >> 6;
    if (lane == 0) { rA[wid] = s1; rB[wid] = s2; }
    __syncthreads();
    float tot1 = rA[0] + rA[1] + rA[2] + rA[3];
    float tot2 = rB[0] + rB[1] + rB[2] + rB[3];
    float mu = tot1 * (1.0f / CF);
    float var = tot2 * (1.0f / CF) - mu * mu;
    float rs = rsqrtf(var + 1e-5f);
    float xh = (v - mu) * rs * lnw[i] + lnb[i];
    float si = silu_f(xh);
    float bs[8]; bspline8(xh, bs);
    float p0 = si * cbw[i], p1 = si * cbw[CF + i];
    float sp0 = 0.f, sp1 = 0.f;
#pragma unroll
    for (int c = 0; c < 8; ++c) {
        sp0 += bs[c] * csw[(size_t)i * 8 + c];
        sp1 += bs[c] * csw[(size_t)(CF + i) * 8 + c];
    }
    p0 += sp0 * csc[i];
    p1 += sp1 * csc[CF + i];
#pragma unroll
    for (int off = 32; off > 0; off >>= 1) {
        p0 += __shfl_xor(p0, off);
        p1 += __shfl_xor(p1, off);
    }
    if (lane == 0) { rP0[wid] = p0; rP1[wid] = p1; }
    __syncthreads();
    if (i < 64) {
        int b = n >> 6;
        float cf = conf[b * 64 + i];
        float mx = cf;
#pragma unroll
        for (int off = 32; off > 0; off >>= 1) mx = fmaxf(mx, __shfl_xor(mx, off));
        float ev = expf(cf - mx);
        float sum = ev;
#pragma unroll
        for (int off = 32; off > 0; off >>= 1) sum += __shfl_xor(sum, off);
        if (i == 0) {
            float wself = expf(conf[n] - mx) / sum;
            float l0 = rP0[0] + rP0[1] + rP0[2] + rP0[3];
            float l1 = rP1[0] + rP1[1] + rP1[2] + rP1[3];
            atomicAdd(&out[b * 2 + 0], wself * l0);
            atomicAdd(&out[b * 2 + 1], wself * l1);
        }
    }
}

extern "C" void kernel_launch(void* const* d_in, const int* in_sizes, int n_in,
                              void* d_out, int out_size, void* d_ws, size_t ws_size,
                              hipStream_t stream) {
    const float* fpn      = (const float*)d_in[0];
    const float* seg      = (const float*)d_in[1];
    const float* ln_r_w   = (const float*)d_in[2];
    const float* ln_r_b   = (const float*)d_in[3];
    const float* ln_h_w   = (const float*)d_in[4];
    const float* ln_h_b   = (const float*)d_in[5];
    const float* router_w = (const float*)d_in[6];
    const float* router_b = (const float*)d_in[7];
    const float* bw1      = (const float*)d_in[8];
    const float* sw1      = (const float*)d_in[9];
    const float* sc1      = (const float*)d_in[10];
    const float* bw2      = (const float*)d_in[11];
    const float* sw2      = (const float*)d_in[12];
    const float* sc2      = (const float*)d_in[13];
    const float* cls_bw   = (const float*)d_in[14];
    const float* cls_sw   = (const float*)d_in[15];
    const float* cls_sc   = (const float*)d_in[16];
    float* out = (float*)d_out;

    float* ws = (float*)d_ws;
    float* vec    = ws;                    // 131072
    float* scores = vec + 131072;          // 4096
    float* cw     = scores + 4096;         // 4096
    float* conf   = cw + 4096;             // 512
    float* yall   = conf + 512;            // 8*512*256 = 1048576
    unsigned short* A1b = (unsigned short*)(yall + 1048576);   // 512*2304
    unsigned short* W1b = A1b + (size_t)NTOK * K1;             // 8*170*2304
    unsigned short* A2b = W1b + (size_t)NE * HID * K1;         // 8*512*1536
    unsigned short* W2b = A2b + (size_t)NE * NTOK * K2P;       // 8*256*1536

    mega_front_kernel<<<dim3(8192 + NE * HID + 2048), dim3(256), 0, stream>>>(
        fpn, seg, bw1, sw1, sc1, bw2, sw2, sc2, vec, W1b, W2b, out);
    ln_score_a1_kernel<<<dim3(NTOK), dim3(256), 0, stream>>>(vec, ln_r_w, ln_r_b, router_w,
                                                             router_b, scores, A1b, A2b);
    // layer1 GEMM: 1D grid, expert = bid%8 (XCD-pinned); last block runs topk
    gemm_mfma_kernel<1, 3, 24><<<dim3(NE * 24 + 1), dim3(256), 0, stream>>>(
        A1b, W1b, nullptr, A2b, scores, cw, conf, HID, K1, 0L, (long)HID * K1, 0L, 0);
    // layer2 GEMM: 1D grid, expert = bid%8 (XCD-pinned) -> yall
    gemm_mfma_kernel<0, 4, 32><<<dim3(NE * 32), dim3(256), 0, stream>>>(
        A2b, W2b, yall, nullptr, nullptr, nullptr, nullptr, CF, K2P, (long)NTOK * K2P,
        (long)CF * K2P, (long)NTOK * CF, CF);
    combcls_kernel<<<dim3(NTOK), dim3(256), 0, stream>>>(yall, cw, conf, ln_h_w, ln_h_b,
                                                         cls_bw, cls_sw, cls_sc, out);
}

// Round 17
// 109.074 us; speedup vs baseline: 1.3150x; 1.3150x over previous
//
#include <hip/hip_runtime.h>
#include <math.h>

#define CF 256
#define HID 170
#define NE 8
#define NTOK 512
#define K1 2304      // 256*9
#define K2P 1536     // 170*9 = 1530 padded to 1536
#define CAPACITY 161

typedef __bf16 bf16x8 __attribute__((ext_vector_type(8)));
typedef unsigned short u16x8 __attribute__((ext_vector_type(8)));
typedef float f32x4 __attribute__((ext_vector_type(4)));

__device__ __forceinline__ float silu_f(float x) { return x / (1.0f + expf(-x)); }
__device__ __forceinline__ float gelu_f(float x) {
    return 0.5f * x * (1.0f + erff(x * 0.70710678118654752f));
}

__device__ __forceinline__ unsigned short f2bf(float f) {
    unsigned int u = __float_as_uint(f);
    u = u + 0x7fffu + ((u >> 16) & 1u);
    return (unsigned short)(u >> 16);
}

// Cubic B-spline bases on uniform grid g(j) = (j-3)*0.4 - 1; denominators are k*h
__device__ __forceinline__ void bspline8(float x, float bs[8]) {
    float b[11];
#pragma unroll
    for (int j = 0; j < 11; ++j) {
        float g0 = (float)(j - 3) * 0.4f - 1.0f;
        float g1 = (float)(j - 2) * 0.4f - 1.0f;
        b[j] = (x >= g0 && x < g1) ? 1.0f : 0.0f;
    }
#pragma unroll
    for (int k = 1; k <= 3; ++k) {
        float inv = 2.5f / (float)k;  // 1/(k*0.4)
#pragma unroll
        for (int j = 0; j < 10 - (k - 1); ++j) {
            float gj   = (float)(j - 3) * 0.4f - 1.0f;
            float gjk1 = (float)(j - 2 + k) * 0.4f - 1.0f;
            b[j] = (x - gj) * inv * b[j] + (gjk1 - x) * inv * b[j + 1];
        }
    }
#pragma unroll
    for (int c = 0; c < 8; ++c) bs[c] = b[c];
}

// ---- 1. mega: pool (0..8191) + buildW1 + buildW2 ---------------------------
__global__ __launch_bounds__(256) void mega_front_kernel(const float* __restrict__ fpn,
                                                         const float* __restrict__ seg,
                                                         const float* __restrict__ bw1,
                                                         const float* __restrict__ sw1,
                                                         const float* __restrict__ sc1,
                                                         const float* __restrict__ bw2,
                                                         const float* __restrict__ sw2,
                                                         const float* __restrict__ sc2,
                                                         float* __restrict__ vec,
                                                         unsigned short* __restrict__ W1,
                                                         unsigned short* __restrict__ W2,
                                                         float* __restrict__ out) {
    int id = blockIdx.x, tid = threadIdx.x;
    if (id == 8192 && tid < 16) out[tid] = 0.0f;  // zero d_out for atomic finalize
    if (id < 8192) {
        // ---- pool: one block per (b, c, bd-octant); 8 float4 loads/thread ----
        int c = id & 255, bd = (id >> 8) & 3, b = id >> 10;
        const float* src = (c < 254) ? fpn + (size_t)(b * 254 + c) * 32768
                                     : seg + (size_t)(b * 2 + (c - 254)) * 32768;
        const float4* s4 = (const float4*)src + (size_t)bd * 8 * 256;
        float s = 0.0f;
#pragma unroll
        for (int it = 0; it < 8; ++it) {
            float4 v = s4[it * 256 + tid];
            s += v.x + v.y + v.z + v.w;
        }
        __shared__ float acc[16];
        if (tid < 16) acc[tid] = 0.0f;
        __syncthreads();
        int bh = tid >> 6, bw = (tid & 7) >> 1;
        atomicAdd(&acc[bh * 4 + bw], s);
        __syncthreads();
        if (tid < 16)
            vec[(size_t)(b * 64 + bd * 16 + tid) * CF + c] = acc[tid] * (1.0f / 512.0f);
    } else if (id < 8192 + NE * HID) {
        // ---- build W1 (augmented bf16) ----
        int r = id - 8192;
        int o = r % HID, e = r / HID, i = tid;
        size_t oi = (size_t)(e * HID + o) * CF + i;
        unsigned short* row = W1 + (size_t)(e * HID + o) * K1;
        row[i] = f2bf(bw1[oi]);
        float sc = sc1[oi];
        const float* sw = sw1 + oi * 8;
        u16x8 pk;
#pragma unroll
        for (int c = 0; c < 8; ++c) pk[c] = f2bf(sw[c] * sc);
        *(u16x8*)(row + CF + i * 8) = pk;
    } else {
        // ---- build W2 (augmented bf16, K padded to 1536) ----
        int r = id - (8192 + NE * HID);
        int o = r & 255, e = r >> 8, t = tid;
        unsigned short* row = W2 + (size_t)(e * CF + o) * K2P;
        if (t < HID) {
            size_t oi = (size_t)(e * CF + o) * HID + t;
            row[t] = f2bf(bw2[oi]);
            float sc = sc2[oi];
            const float* sw = sw2 + oi * 8;
            u16x8 pk;
#pragma unroll
            for (int c = 0; c < 8; ++c) pk[c] = f2bf(sw[c] * sc);
            *(u16x8*)(row + HID + t * 8) = pk;
        } else if (t < HID + 6) {
            row[HID * 9 + (t - HID)] = 0;
        }
    }
}

// ---- 2. per-token layernorm + router scores + A1 build + A2-pad zero -------
__global__ __launch_bounds__(256) void ln_score_a1_kernel(const float* __restrict__ vec,
                                                          const float* __restrict__ lnw,
                                                          const float* __restrict__ lnb,
                                                          const float* __restrict__ rw,
                                                          const float* __restrict__ rb,
                                                          float* __restrict__ scores,
                                                          unsigned short* __restrict__ A1,
                                                          unsigned short* __restrict__ A2) {
    int n = blockIdx.x, i = threadIdx.x;
    // zero A2 K-pad [1530,1536) for this token across all experts
    if (i < 48) {
        int e = i / 6, j = i - e * 6;
        A2[((size_t)e * NTOK + n) * K2P + HID * 9 + j] = 0;
    }
    float v = vec[(size_t)n * CF + i];
    float s1 = v, s2 = v * v;
#pragma unroll
    for (int off = 32; off > 0; off >>= 1) {
        s1 += __shfl_xor(s1, off);
        s2 += __shfl_xor(s2, off);
    }
    __shared__ float rs1[4], rs2[4];
    int lane = i & 63, wid = i >> 6;
    if (lane == 0) { rs1[wid] = s1; rs2[wid] = s2; }
    __syncthreads();
    float tot1 = rs1[0] + rs1[1] + rs1[2] + rs1[3];
    float tot2 = rs2[0] + rs2[1] + rs2[2] + rs2[3];
    float mu = tot1 * (1.0f / CF);
    float var = tot2 * (1.0f / CF) - mu * mu;
    float rsd = rsqrtf(var + 1e-5f);
    float xv = (v - mu) * rsd * lnw[i] + lnb[i];
    unsigned short* r = A1 + (size_t)n * K1;
    r[i] = f2bf(silu_f(xv));
    float bs[8]; bspline8(xv, bs);
    u16x8 pk;
#pragma unroll
    for (int c = 0; c < 8; ++c) pk[c] = f2bf(bs[c]);
    *(u16x8*)(r + CF + i * 8) = pk;
    float p[NE];
#pragma unroll
    for (int e = 0; e < NE; ++e) p[e] = xv * rw[e * CF + i];
#pragma unroll
    for (int off = 32; off > 0; off >>= 1)
#pragma unroll
        for (int e = 0; e < NE; ++e) p[e] += __shfl_xor(p[e], off);
    __shared__ float pacc[4][NE];
    if (lane == 0)
#pragma unroll
        for (int e = 0; e < NE; ++e) pacc[wid][e] = p[e];
    __syncthreads();
    if (i < NE)
        scores[n * NE + i] = pacc[0][i] + pacc[1][i] + pacc[2][i] + pacc[3][i] + rb[i];
}

// ---- 3. batched bf16 MFMA GEMM, 64x64 tile, BK=256, 512 threads ------------
// 8 waves = 2 waves/SIMD (latency hiding): wave w -> quadrant wrc=w&3 and
// K-half kh=w>>2 (ks 0-3 / 4-7); partial accs summed via LDS at the end.
// 1D grid, bid%8 = expert (XCD-pinned).
// MODE 1: epilogue gelu->augmented A2; bid==NE*TPE runs topk.
template <int MODE, int NTX, int TPE>
__global__ __launch_bounds__(512) void gemm_mfma_kernel(
        const unsigned short* __restrict__ Ag, const unsigned short* __restrict__ Bg,
        float* __restrict__ C, unsigned short* __restrict__ A2,
        const float* __restrict__ scores, float* __restrict__ cw, float* __restrict__ conf,
        int N, int K, long sA, long sB, long sC, int ldc) {
    __shared__ alignas(16) unsigned char smem[65536];
    int tid = threadIdx.x;
    int lane = tid & 63, w = tid >> 6;

    if (MODE == 1 && blockIdx.x >= NE * TPE) {
        // ---- topk (512 threads: 1 token each, then 4 waves x 2 experts) ----
        int* ti0 = (int*)smem;
        int* ti1 = ti0 + NTOK;
        float* tw0 = (float*)(ti1 + NTOK);
        float* tw1 = tw0 + NTOK;
        {
            int t = tid;
            float m1 = -1e30f, m2 = -1e30f; int i1 = 0, i2 = 0;
#pragma unroll
            for (int e = 0; e < NE; ++e) {
                float sc = scores[t * NE + e];
                if (sc > m1) { m2 = m1; i2 = i1; m1 = sc; i1 = e; }
                else if (sc > m2) { m2 = sc; i2 = e; }
            }
            conf[t] = m1;
            float ew = expf(m2 - m1);
            ti0[t] = i1; ti1[t] = i2;
            tw0[t] = 1.0f / (1.0f + ew); tw1[t] = ew / (1.0f + ew);
        }
        __syncthreads();
        if (w < 4) {
#pragma unroll
            for (int e2 = 0; e2 < 2; ++e2) {
                int e = w * 2 + e2;
                int cnt = 0;
#pragma unroll
                for (int c = 0; c < NTOK / 64; ++c) {
                    int t = c * 64 + lane;
                    int h0 = (ti0[t] == e), h1 = (ti1[t] == e);
                    int sel = h0 | h1;
                    unsigned long long mask = __ballot(sel);
                    int pos = cnt + (int)__popcll(mask & ((1ull << lane) - 1ull));
                    float wv = 0.f;
                    if (sel && pos < CAPACITY) wv = h0 ? tw0[t] : tw1[t];
                    cw[e * NTOK + t] = wv;
                    cnt += (int)__popcll(mask);
                }
            }
        }
        return;
    }

    unsigned char* AsB = smem;            // 64 rows x 512 B
    unsigned char* BsB = smem + 32768;    // 64 rows x 512 B

    // XCD-pinned decode: expert = bid % 8 (1D round-robin -> same XCD)
    int bid = blockIdx.x;
    int e = bid & 7, t = bid >> 3;
    int m0 = (t / NTX) * 64, n0 = (t % NTX) * 64;
    const unsigned short* A = Ag + (size_t)e * sA;
    const unsigned short* B = Bg + (size_t)e * sB;
    int wrc = w & 3, kh = w >> 2;
    int wr = wrc >> 1, wc = wrc & 1;
    int fr = lane & 15, fg = lane >> 4;

    // staging: thread covers rows r0+16q (q=0..3), fixed 16B chunk ch
    int r0 = tid >> 5, ch = tid & 31;                   // r0 0..15
    int d0 = r0 * 512 + ((ch * 16) ^ ((r0 & 7) << 4));  // (r0+16q)&7 == r0&7
    const unsigned short* aP = A + (size_t)(m0 + r0) * K + ch * 8;
    const unsigned short* bP = B + (size_t)(n0 + r0) * K + ch * 8;
    bool bOk[4];
#pragma unroll
    for (int q = 0; q < 4; ++q) bOk[q] = (n0 + r0 + q * 16) < N;
    const u16x8 zero8 = {0, 0, 0, 0, 0, 0, 0, 0};

    f32x4 acc[2][2];
#pragma unroll
    for (int i = 0; i < 2; ++i)
#pragma unroll
        for (int j = 0; j < 2; ++j)
#pragma unroll
            for (int r = 0; r < 4; ++r) acc[i][j][r] = 0.f;

    const int steps = K >> 8;  // 9 (gemm1) or 6 (gemm2)
    u16x8 ra[4], rb[4];
#pragma unroll
    for (int q = 0; q < 4; ++q) {
        ra[q] = *(const u16x8*)(aP + (size_t)q * 16 * K);
        rb[q] = bOk[q] ? *(const u16x8*)(bP + (size_t)q * 16 * K) : zero8;
    }

    for (int s = 0; s < steps; ++s) {
        __syncthreads();
#pragma unroll
        for (int q = 0; q < 4; ++q) {
            *(u16x8*)(AsB + d0 + q * 8192) = ra[q];
            *(u16x8*)(BsB + d0 + q * 8192) = rb[q];
        }
        __syncthreads();
        if (s + 1 < steps) {
            int k0 = (s + 1) << 8;
#pragma unroll
            for (int q = 0; q < 4; ++q) {
                ra[q] = *(const u16x8*)(aP + (size_t)q * 16 * K + k0);
                rb[q] = bOk[q] ? *(const u16x8*)(bP + (size_t)q * 16 * K + k0) : zero8;
            }
        }
#pragma unroll
        for (int ks = 0; ks < 4; ++ks) {
            int kb = ((kh << 2) + ks) * 64 + fg * 16;
            u16x8 af[2], bf[2];
#pragma unroll
            for (int mf = 0; mf < 2; ++mf) {
                int row = wr * 32 + mf * 16 + fr;
                af[mf] = *(const u16x8*)(AsB + row * 512 + (kb ^ ((row & 7) << 4)));
            }
#pragma unroll
            for (int nf = 0; nf < 2; ++nf) {
                int row = wc * 32 + nf * 16 + fr;
                bf[nf] = *(const u16x8*)(BsB + row * 512 + (kb ^ ((row & 7) << 4)));
            }
#pragma unroll
            for (int mf = 0; mf < 2; ++mf)
#pragma unroll
                for (int nf = 0; nf < 2; ++nf)
                    acc[mf][nf] = __builtin_amdgcn_mfma_f32_16x16x32_bf16(
                        __builtin_bit_cast(bf16x8, af[mf]),
                        __builtin_bit_cast(bf16x8, bf[nf]), acc[mf][nf], 0, 0, 0);
        }
    }

    // ---- cross-wave K-half reduction: kh=1 partials -> LDS -> kh=0 adds ----
    __syncthreads();
    float* xch = (float*)smem;  // 4 quadrants x 64 lanes x 16 f32 = 16 KB
    if (kh == 1) {
#pragma unroll
        for (int mf = 0; mf < 2; ++mf)
#pragma unroll
            for (int nf = 0; nf < 2; ++nf)
#pragma unroll
                for (int r = 0; r < 4; ++r)
                    xch[(wrc * 64 + lane) * 16 + (mf * 2 + nf) * 4 + r] = acc[mf][nf][r];
    }
    __syncthreads();
    if (kh == 1) return;
#pragma unroll
    for (int mf = 0; mf < 2; ++mf)
#pragma unroll
        for (int nf = 0; nf < 2; ++nf)
#pragma unroll
            for (int r = 0; r < 4; ++r)
                acc[mf][nf][r] += xch[(wrc * 64 + lane) * 16 + (mf * 2 + nf) * 4 + r];

    if (MODE == 1) {
#pragma unroll
        for (int mf = 0; mf < 2; ++mf)
#pragma unroll
            for (int nf = 0; nf < 2; ++nf)
#pragma unroll
                for (int r = 0; r < 4; ++r) {
                    int row = m0 + wr * 32 + mf * 16 + fg * 4 + r;  // token
                    int col = n0 + wc * 32 + nf * 16 + fr;          // hid
                    if (col < N) {
                        float g = gelu_f(acc[mf][nf][r]);
                        unsigned short* rr = A2 + ((size_t)e * NTOK + row) * K2P;
                        rr[col] = f2bf(silu_f(g));
                        float bs[8]; bspline8(g, bs);
                        u16x8 pk;
#pragma unroll
                        for (int c = 0; c < 8; ++c) pk[c] = f2bf(bs[c]);
                        *(u16x8*)(rr + HID + col * 8) = pk;
                    }
                }
    } else {
        float* Ce = C + (size_t)e * sC;
#pragma unroll
        for (int mf = 0; mf < 2; ++mf)
#pragma unroll
            for (int nf = 0; nf < 2; ++nf)
#pragma unroll
                for (int r = 0; r < 4; ++r) {
                    int row = m0 + wr * 32 + mf * 16 + fg * 4 + r;
                    int col = n0 + wc * 32 + nf * 16 + fr;
                    if (col < N) Ce[(size_t)row * ldc + col] = acc[mf][nf][r];
                }
    }
}

// ---- 4. combine + classifier KAN + atomic batch-softmax finalize -----------
__global__ __launch_bounds__(256) void combcls_kernel(const float* __restrict__ y,
                                                      const float* __restrict__ cw,
                                                      const float* __restrict__ conf,
                                                      const float* __restrict__ lnw,
                                                      const float* __restrict__ lnb,
                                                      const float* __restrict__ cbw,
                                                      const float* __restrict__ csw,
                                                      const float* __restrict__ csc,
                                                      float* __restrict__ out) {
    int n = blockIdx.x, i = threadIdx.x;
    float v = 0.f;
#pragma unroll
    for (int e = 0; e < NE; ++e)
        v += cw[e * NTOK + n] * y[((size_t)(e * NTOK + n)) * CF + i];
    float s1 = v, s2 = v * v;
#pragma unroll
    for (int off = 32; off > 0; off >>= 1) {
        s1 += __shfl_xor(s1, off);
        s2 += __shfl_xor(s2, off);
    }
    __shared__ float rA[4], rB[4], rP0[4], rP1[4];
    int lane = i & 63, wid = i >> 6;
    if (lane == 0) { rA[wid] = s1; rB[wid] = s2; }
    __syncthreads();
    float tot1 = rA[0] + rA[1] + rA[2] + rA[3];
    float tot2 = rB[0] + rB[1] + rB[2] + rB[3];
    float mu = tot1 * (1.0f / CF);
    float var = tot2 * (1.0f / CF) - mu * mu;
    float rs = rsqrtf(var + 1e-5f);
    float xh = (v - mu) * rs * lnw[i] + lnb[i];
    float si = silu_f(xh);
    float bs[8]; bspline8(xh, bs);
    float p0 = si * cbw[i], p1 = si * cbw[CF + i];
    float sp0 = 0.f, sp1 = 0.f;
#pragma unroll
    for (int c = 0; c < 8; ++c) {
        sp0 += bs[c] * csw[(size_t)i * 8 + c];
        sp1 += bs[c] * csw[(size_t)(CF + i) * 8 + c];
    }
    p0 += sp0 * csc[i];
    p1 += sp1 * csc[CF + i];
#pragma unroll
    for (int off = 32; off > 0; off >>= 1) {
        p0 += __shfl_xor(p0, off);
        p1 += __shfl_xor(p1, off);
    }
    if (lane == 0) { rP0[wid] = p0; rP1[wid] = p1; }
    __syncthreads();
    if (i < 64) {
        int b = n >> 6;
        float cf = conf[b * 64 + i];
        float mx = cf;
#pragma unroll
        for (int off = 32; off > 0; off >>= 1) mx = fmaxf(mx, __shfl_xor(mx, off));
        float ev = expf(cf - mx);
        float sum = ev;
#pragma unroll
        for (int off = 32; off > 0; off >>= 1) sum += __shfl_xor(sum, off);
        if (i == 0) {
            float wself = expf(conf[n] - mx) / sum;
            float l0 = rP0[0] + rP0[1] + rP0[2] + rP0[3];
            float l1 = rP1[0] + rP1[1] + rP1[2] + rP1[3];
            atomicAdd(&out[b * 2 + 0], wself * l0);
            atomicAdd(&out[b * 2 + 1], wself * l1);
        }
    }
}

extern "C" void kernel_launch(void* const* d_in, const int* in_sizes, int n_in,
                              void* d_out, int out_size, void* d_ws, size_t ws_size,
                              hipStream_t stream) {
    const float* fpn      = (const float*)d_in[0];
    const float* seg      = (const float*)d_in[1];
    const float* ln_r_w   = (const float*)d_in[2];
    const float* ln_r_b   = (const float*)d_in[3];
    const float* ln_h_w   = (const float*)d_in[4];
    const float* ln_h_b   = (const float*)d_in[5];
    const float* router_w = (const float*)d_in[6];
    const float* router_b = (const float*)d_in[7];
    const float* bw1      = (const float*)d_in[8];
    const float* sw1      = (const float*)d_in[9];
    const float* sc1      = (const float*)d_in[10];
    const float* bw2      = (const float*)d_in[11];
    const float* sw2      = (const float*)d_in[12];
    const float* sc2      = (const float*)d_in[13];
    const float* cls_bw   = (const float*)d_in[14];
    const float* cls_sw   = (const float*)d_in[15];
    const float* cls_sc   = (const float*)d_in[16];
    float* out = (float*)d_out;

    float* ws = (float*)d_ws;
    float* vec    = ws;                    // 131072
    float* scores = vec + 131072;          // 4096
    float* cw     = scores + 4096;         // 4096
    float* conf   = cw + 4096;             // 512
    float* yall   = conf + 512;            // 8*512*256 = 1048576
    unsigned short* A1b = (unsigned short*)(yall + 1048576);   // 512*2304
    unsigned short* W1b = A1b + (size_t)NTOK * K1;             // 8*170*2304
    unsigned short* A2b = W1b + (size_t)NE * HID * K1;         // 8*512*1536
    unsigned short* W2b = A2b + (size_t)NE * NTOK * K2P;       // 8*256*1536

    mega_front_kernel<<<dim3(8192 + NE * HID + 2048), dim3(256), 0, stream>>>(
        fpn, seg, bw1, sw1, sc1, bw2, sw2, sc2, vec, W1b, W2b, out);
    ln_score_a1_kernel<<<dim3(NTOK), dim3(256), 0, stream>>>(vec, ln_r_w, ln_r_b, router_w,
                                                             router_b, scores, A1b, A2b);
    // layer1 GEMM: 512-thread blocks (2 waves/SIMD); last block runs topk
    gemm_mfma_kernel<1, 3, 24><<<dim3(NE * 24 + 1), dim3(512), 0, stream>>>(
        A1b, W1b, nullptr, A2b, scores, cw, conf, HID, K1, 0L, (long)HID * K1, 0L, 0);
    // layer2 GEMM: 512-thread blocks -> yall
    gemm_mfma_kernel<0, 4, 32><<<dim3(NE * 32), dim3(512), 0, stream>>>(
        A2b, W2b, yall, nullptr, nullptr, nullptr, nullptr, CF, K2P, (long)NTOK * K2P,
        (long)CF * K2P, (long)NTOK * CF, CF);
    combcls_kernel<<<dim3(NTOK), dim3(256), 0, stream>>>(yall, cw, conf, ln_h_w, ln_h_b,
                                                         cls_bw, cls_sw, cls_sc, out);
}